// Round 1
// baseline (413.554 us; speedup 1.0000x reference)
//
#include <hip/hip_runtime.h>

// MultiHeadedAttention with relative position (B=2, T=1024, D=1024, H=16, DK=64)
// Pipeline: proj(q,k,v) -> S=Bp+bias+mask -> S=softmax(qk^T+S) in-place ->
//           X0=attn@pos_v -> X=X0+attn@v -> out=X@Wo+bo
// All matmuls bf16 MFMA 16x16x32 with fp32 accum; abs threshold 6.4e-3 permits.

#define DEV __device__ __forceinline__

typedef short bf16x8 __attribute__((ext_vector_type(8)));
typedef float f32x4 __attribute__((ext_vector_type(4)));

DEV short f2b(float f) {
  unsigned u = __builtin_bit_cast(unsigned, f);
  u = (u + 0x7FFFu + ((u >> 16) & 1u)) >> 16;
  return (short)u;
}
DEV float b2f(short s) {
  unsigned u = ((unsigned)(unsigned short)s) << 16;
  return __builtin_bit_cast(float, u);
}

#define MFMA(a, b, c) __builtin_amdgcn_mfma_f32_16x16x32_bf16(a, b, c, 0, 0, 0)

// ---------------------------------------------------------------------------
// K1: projection GEMM: out[(b,h,t,dk)] = bf16( (in[(b,t),:] @ W + bias) * scale )
// M=2048 (b*T+t), N=1024 (h*64+dk), K=1024. BM=BN=64, BK=32, 4 waves.
__global__ __launch_bounds__(256) void k_proj(
    const float* __restrict__ in, const float* __restrict__ W,
    const float* __restrict__ bias, short* __restrict__ out, float scale) {
  __shared__ short As[64][40];  // [m][k], +8 pad
  __shared__ short Bs[64][40];  // [n][k] (transposed), +8 pad
  const int n0 = blockIdx.x * 64;
  const int m0 = blockIdx.y * 64;
  const int tid = threadIdx.x;
  const int w = tid >> 6, l = tid & 63, lg = l >> 4, lr = l & 15;
  const int wm = (w >> 1) * 2, wn = (w & 1) * 2;  // 16-tile units
  f32x4 acc[2][2] = {};
  for (int k0 = 0; k0 < 1024; k0 += 32) {
#pragma unroll
    for (int rr = 0; rr < 2; ++rr) {  // stage A 64x32 fp32 -> bf16
      int r = (tid >> 3) + rr * 32, c4 = (tid & 7) * 4;
      const float4 vA = *(const float4*)(in + (size_t)(m0 + r) * 1024 + k0 + c4);
      As[r][c4 + 0] = f2b(vA.x); As[r][c4 + 1] = f2b(vA.y);
      As[r][c4 + 2] = f2b(vA.z); As[r][c4 + 3] = f2b(vA.w);
    }
#pragma unroll
    for (int rr = 0; rr < 2; ++rr) {  // stage B 32x64 fp32 -> bf16 transposed
      int kk = (tid >> 4) + rr * 16, n4 = (tid & 15) * 4;
      const float4 vB = *(const float4*)(W + (size_t)(k0 + kk) * 1024 + n0 + n4);
      Bs[n4 + 0][kk] = f2b(vB.x); Bs[n4 + 1][kk] = f2b(vB.y);
      Bs[n4 + 2][kk] = f2b(vB.z); Bs[n4 + 3][kk] = f2b(vB.w);
    }
    __syncthreads();
    bf16x8 af[2], bfr[2];
#pragma unroll
    for (int mi = 0; mi < 2; ++mi) af[mi] = *(const bf16x8*)&As[(wm + mi) * 16 + lr][lg * 8];
#pragma unroll
    for (int ni = 0; ni < 2; ++ni) bfr[ni] = *(const bf16x8*)&Bs[(wn + ni) * 16 + lr][lg * 8];
#pragma unroll
    for (int mi = 0; mi < 2; ++mi)
#pragma unroll
      for (int ni = 0; ni < 2; ++ni) acc[mi][ni] = MFMA(af[mi], bfr[ni], acc[mi][ni]);
    __syncthreads();
  }
#pragma unroll
  for (int mi = 0; mi < 2; ++mi)
#pragma unroll
    for (int ni = 0; ni < 2; ++ni)
#pragma unroll
      for (int r = 0; r < 4; ++r) {
        int m = m0 + (wm + mi) * 16 + lg * 4 + r;
        int n = n0 + (wn + ni) * 16 + lr;
        float val = (acc[mi][ni][r] + bias[n]) * scale;
        int b = m >> 10, t = m & 1023, h = n >> 6, dk = n & 63;
        out[((size_t)(b * 16 + h) * 1024 + t) * 64 + dk] = f2b(val);
      }
}

// ---------------------------------------------------------------------------
// K2a: S[bh,t,s] = q[bh,t,:]·pos_k[t,s,:] + bias[h,t,s]  (or -1e30 if masked)
// grid (s/256, t); block 256 = 4 waves, each wave 64 cols; M=32 (bh).
__global__ __launch_bounds__(256) void k_posk_bias(
    const short* __restrict__ q, const float* __restrict__ pos_k,
    const float* __restrict__ rab, const int* __restrict__ mask,
    short* __restrict__ S) {
  const int t = blockIdx.y;
  const int tid = threadIdx.x;
  const int w = tid >> 6, l = tid & 63, lg = l >> 4, lr = l & 15;
  const int s0 = blockIdx.x * 256 + w * 64;
  bf16x8 af[2][2];
#pragma unroll
  for (int mi = 0; mi < 2; ++mi)
#pragma unroll
    for (int kk = 0; kk < 2; ++kk) {
      int bh = mi * 16 + lr;
      af[mi][kk] = *(const bf16x8*)(q + ((size_t)bh * 1024 + t) * 64 + kk * 32 + lg * 8);
    }
  f32x4 acc[2][4] = {};
#pragma unroll
  for (int ni = 0; ni < 4; ++ni) {
    int s = s0 + ni * 16 + lr;
#pragma unroll
    for (int kk = 0; kk < 2; ++kk) {
      const float* pk = pos_k + ((size_t)t * 1024 + s) * 64 + kk * 32 + lg * 8;
      const float4 p0 = *(const float4*)pk;
      const float4 p1 = *(const float4*)(pk + 4);
      bf16x8 bfr;
      bfr[0] = f2b(p0.x); bfr[1] = f2b(p0.y); bfr[2] = f2b(p0.z); bfr[3] = f2b(p0.w);
      bfr[4] = f2b(p1.x); bfr[5] = f2b(p1.y); bfr[6] = f2b(p1.z); bfr[7] = f2b(p1.w);
#pragma unroll
      for (int mi = 0; mi < 2; ++mi) acc[mi][ni] = MFMA(af[mi][kk], bfr, acc[mi][ni]);
    }
  }
#pragma unroll
  for (int ni = 0; ni < 4; ++ni) {
    int s = s0 + ni * 16 + lr;
    int msk0 = mask[(size_t)t * 1024 + s];
    int msk1 = mask[(size_t)(1024 + t) * 1024 + s];
#pragma unroll
    for (int r = 0; r < 4; ++r) {
      int h = lg * 4 + r;  // same h for both b (rows mi*16+h)
      float bv = rab[((size_t)h * 1024 + t) * 1024 + s];
      float v0 = acc[0][ni][r] + bv;
      float v1 = acc[1][ni][r] + bv;
      if (msk0 == 0) v0 = -1e30f;
      if (msk1 == 0) v1 = -1e30f;
      S[((size_t)h * 1024 + t) * 1024 + s] = f2b(v0);
      S[((size_t)(16 + h) * 1024 + t) * 1024 + s] = f2b(v1);
    }
  }
}

// ---------------------------------------------------------------------------
// K2b: S = softmax_rows( q@k^T + S ), in place. grid (T/32, bh); 8 waves.
// Wave (wm,wn): rows wm*16..+16, cols wn*256..+256 -> 16 n-tiles in acc.
__global__ __launch_bounds__(512) void k_attn_softmax(
    const short* __restrict__ q, const short* __restrict__ kmat,
    short* __restrict__ S) {
  const int bh = blockIdx.y;
  const int tid = threadIdx.x;
  const int w = tid >> 6, l = tid & 63, lg = l >> 4, lr = l & 15;
  const int wm = w >> 2, wn = w & 3;
  const int t0 = blockIdx.x * 32 + wm * 16;
  const int scol = wn * 256;
  __shared__ float redA[32][4];
  __shared__ float redB[32][4];

  bf16x8 af[2];
#pragma unroll
  for (int kk = 0; kk < 2; ++kk)
    af[kk] = *(const bf16x8*)(q + ((size_t)bh * 1024 + (t0 + lr)) * 64 + kk * 32 + lg * 8);

  f32x4 acc[16];
#pragma unroll
  for (int ni = 0; ni < 16; ++ni) {
    int s = scol + ni * 16 + lr;
    const short* kp = kmat + ((size_t)bh * 1024 + s) * 64 + lg * 8;
    bf16x8 b0 = *(const bf16x8*)kp;
    bf16x8 b1 = *(const bf16x8*)(kp + 32);
    f32x4 a = {};
    a = MFMA(af[0], b0, a);
    a = MFMA(af[1], b1, a);
    acc[ni] = a;
  }
#pragma unroll
  for (int ni = 0; ni < 16; ++ni)
#pragma unroll
    for (int r = 0; r < 4; ++r) {
      int tt = t0 + lg * 4 + r;
      int s = scol + ni * 16 + lr;
      acc[ni][r] += b2f(S[((size_t)bh * 1024 + tt) * 1024 + s]);
    }
  float pm[4];
#pragma unroll
  for (int r = 0; r < 4; ++r) {
    float m = acc[0][r];
#pragma unroll
    for (int ni = 1; ni < 16; ++ni) m = fmaxf(m, acc[ni][r]);
    m = fmaxf(m, __shfl_xor(m, 1));
    m = fmaxf(m, __shfl_xor(m, 2));
    m = fmaxf(m, __shfl_xor(m, 4));
    m = fmaxf(m, __shfl_xor(m, 8));
    pm[r] = m;
  }
  if (lr == 0) {
#pragma unroll
    for (int r = 0; r < 4; ++r) redA[wm * 16 + lg * 4 + r][wn] = pm[r];
  }
  __syncthreads();
  float rowm[4];
#pragma unroll
  for (int r = 0; r < 4; ++r) {
    int row = wm * 16 + lg * 4 + r;
    rowm[r] = fmaxf(fmaxf(redA[row][0], redA[row][1]), fmaxf(redA[row][2], redA[row][3]));
  }
  float rs[4];
#pragma unroll
  for (int r = 0; r < 4; ++r) {
    float sum = 0.f;
#pragma unroll
    for (int ni = 0; ni < 16; ++ni) {
      float e = __expf(acc[ni][r] - rowm[r]);
      acc[ni][r] = e;
      sum += e;
    }
    sum += __shfl_xor(sum, 1);
    sum += __shfl_xor(sum, 2);
    sum += __shfl_xor(sum, 4);
    sum += __shfl_xor(sum, 8);
    rs[r] = sum;
  }
  if (lr == 0) {
#pragma unroll
    for (int r = 0; r < 4; ++r) redB[wm * 16 + lg * 4 + r][wn] = rs[r];
  }
  __syncthreads();
#pragma unroll
  for (int r = 0; r < 4; ++r) {
    int row = wm * 16 + lg * 4 + r;
    float inv = 1.0f / (redB[row][0] + redB[row][1] + redB[row][2] + redB[row][3]);
    int tt = t0 + lg * 4 + r;
#pragma unroll
    for (int ni = 0; ni < 16; ++ni) {
      int s = scol + ni * 16 + lr;
      S[((size_t)bh * 1024 + tt) * 1024 + s] = f2b(acc[ni][r] * inv);
    }
  }
}

// ---------------------------------------------------------------------------
// K3: X0[b,t,h*64+dk] = sum_s attn[bh,t,s] * pos_v[t,s,dk].  grid (T); 4 waves.
// pos_v chunk transposed into LDS so B-fragments are contiguous ds_read_b128.
__global__ __launch_bounds__(256) void k_posv(
    const short* __restrict__ S, const float* __restrict__ pos_v,
    float* __restrict__ X0) {
  const int t = blockIdx.x;
  const int tid = threadIdx.x;
  const int w = tid >> 6, l = tid & 63, lg = l >> 4, lr = l & 15;
  const int mi = w >> 1;          // bh tile (0/1)
  const int nb = (w & 1) * 2;     // ntile base
  __shared__ short pvT[64][264];  // [dk][s_chunk], pad 8
  f32x4 acc[2] = {};
  for (int c = 0; c < 4; ++c) {
    int sc = c * 256;
    {
      int dk = tid & 63;
      int sp = (tid >> 6) * 2;
#pragma unroll 8
      for (int it = 0; it < 32; ++it) {
        int s = sp + it * 8;
        float a0 = pos_v[((size_t)t * 1024 + sc + s) * 64 + dk];
        float a1 = pos_v[((size_t)t * 1024 + sc + s + 1) * 64 + dk];
        pvT[dk][s] = f2b(a0);
        pvT[dk][s + 1] = f2b(a1);
      }
    }
    __syncthreads();
#pragma unroll
    for (int kk = 0; kk < 8; ++kk) {
      int bh = mi * 16 + lr;
      bf16x8 afr = *(const bf16x8*)(S + ((size_t)bh * 1024 + t) * 1024 + sc + kk * 32 + lg * 8);
#pragma unroll
      for (int ni = 0; ni < 2; ++ni) {
        int dk = (nb + ni) * 16 + lr;
        bf16x8 bfr = *(const bf16x8*)&pvT[dk][kk * 32 + lg * 8];
        acc[ni] = MFMA(afr, bfr, acc[ni]);
      }
    }
    __syncthreads();
  }
#pragma unroll
  for (int ni = 0; ni < 2; ++ni)
#pragma unroll
    for (int r = 0; r < 4; ++r) {
      int bh = mi * 16 + lg * 4 + r;
      int b = bh >> 4, h = bh & 15;
      int dk = (nb + ni) * 16 + lr;
      X0[((size_t)(b * 1024 + t)) * 1024 + h * 64 + dk] = acc[ni][r];
    }
}

// ---------------------------------------------------------------------------
// K4: X[b,t,h*64+dk] = bf16( X0 + sum_s attn[bh,t,s]*v[bh,s,dk] )
// grid (T/128, bh); block 4 waves, each wave 2 m-tiles x 4 n-tiles.
__global__ __launch_bounds__(256) void k_av(
    const short* __restrict__ S, const short* __restrict__ v,
    const float* __restrict__ X0, short* __restrict__ X) {
  const int bh = blockIdx.y;
  const int tt0 = blockIdx.x * 128;
  const int tid = threadIdx.x;
  const int w = tid >> 6, l = tid & 63, lg = l >> 4, lr = l & 15;
  __shared__ short vT[64][264];
  f32x4 acc[2][4] = {};
  for (int c = 0; c < 4; ++c) {
    int sc = c * 256;
    {
      int pr = tid & 31;    // dk pair
      int sr = tid >> 5;    // 8 s rows per iter
#pragma unroll 8
      for (int it = 0; it < 32; ++it) {
        int s = sr + it * 8;
        short2 sv = *(const short2*)(v + ((size_t)bh * 1024 + sc + s) * 64 + pr * 2);
        vT[pr * 2][s] = sv.x;
        vT[pr * 2 + 1][s] = sv.y;
      }
    }
    __syncthreads();
#pragma unroll
    for (int kk = 0; kk < 8; ++kk) {
      bf16x8 afr[2];
#pragma unroll
      for (int mi = 0; mi < 2; ++mi) {
        int t = tt0 + (w * 2 + mi) * 16 + lr;
        afr[mi] = *(const bf16x8*)(S + ((size_t)bh * 1024 + t) * 1024 + sc + kk * 32 + lg * 8);
      }
#pragma unroll
      for (int ni = 0; ni < 4; ++ni) {
        bf16x8 bfr = *(const bf16x8*)&vT[ni * 16 + lr][kk * 32 + lg * 8];
#pragma unroll
        for (int mi = 0; mi < 2; ++mi) acc[mi][ni] = MFMA(afr[mi], bfr, acc[mi][ni]);
      }
    }
    __syncthreads();
  }
  const int b = bh >> 4, h = bh & 15;
#pragma unroll
  for (int mi = 0; mi < 2; ++mi)
#pragma unroll
    for (int ni = 0; ni < 4; ++ni)
#pragma unroll
      for (int r = 0; r < 4; ++r) {
        int t = tt0 + (w * 2 + mi) * 16 + lg * 4 + r;
        int d = h * 64 + ni * 16 + lr;
        size_t idx = ((size_t)(b * 1024 + t)) * 1024 + d;
        X[idx] = f2b(X0[idx] + acc[mi][ni][r]);
      }
}

// ---------------------------------------------------------------------------
// K5: out = X @ Wo + bo  (fp32 out). Same structure as K1, bf16 A input.
__global__ __launch_bounds__(256) void k_oproj(
    const short* __restrict__ X, const float* __restrict__ W,
    const float* __restrict__ bias, float* __restrict__ out) {
  __shared__ short As[64][40];
  __shared__ short Bs[64][40];
  const int n0 = blockIdx.x * 64;
  const int m0 = blockIdx.y * 64;
  const int tid = threadIdx.x;
  const int w = tid >> 6, l = tid & 63, lg = l >> 4, lr = l & 15;
  const int wm = (w >> 1) * 2, wn = (w & 1) * 2;
  f32x4 acc[2][2] = {};
  for (int k0 = 0; k0 < 1024; k0 += 32) {
    {
      int r = tid >> 2, c8 = (tid & 3) * 8;
      bf16x8 vA = *(const bf16x8*)(X + (size_t)(m0 + r) * 1024 + k0 + c8);
      *(bf16x8*)&As[r][c8] = vA;
    }
#pragma unroll
    for (int rr = 0; rr < 2; ++rr) {
      int kk = (tid >> 4) + rr * 16, n4 = (tid & 15) * 4;
      const float4 vB = *(const float4*)(W + (size_t)(k0 + kk) * 1024 + n0 + n4);
      Bs[n4 + 0][kk] = f2b(vB.x); Bs[n4 + 1][kk] = f2b(vB.y);
      Bs[n4 + 2][kk] = f2b(vB.z); Bs[n4 + 3][kk] = f2b(vB.w);
    }
    __syncthreads();
    bf16x8 af[2], bfr[2];
#pragma unroll
    for (int mi = 0; mi < 2; ++mi) af[mi] = *(const bf16x8*)&As[(wm + mi) * 16 + lr][lg * 8];
#pragma unroll
    for (int ni = 0; ni < 2; ++ni) bfr[ni] = *(const bf16x8*)&Bs[(wn + ni) * 16 + lr][lg * 8];
#pragma unroll
    for (int mi = 0; mi < 2; ++mi)
#pragma unroll
      for (int ni = 0; ni < 2; ++ni) acc[mi][ni] = MFMA(af[mi], bfr[ni], acc[mi][ni]);
    __syncthreads();
  }
#pragma unroll
  for (int mi = 0; mi < 2; ++mi)
#pragma unroll
    for (int ni = 0; ni < 2; ++ni)
#pragma unroll
      for (int r = 0; r < 4; ++r) {
        int m = m0 + (wm + mi) * 16 + lg * 4 + r;
        int n = n0 + (wn + ni) * 16 + lr;
        out[(size_t)m * 1024 + n] = acc[mi][ni][r] + bias[n];
      }
}

// ---------------------------------------------------------------------------
extern "C" void kernel_launch(void* const* d_in, const int* in_sizes, int n_in,
                              void* d_out, int out_size, void* d_ws, size_t ws_size,
                              hipStream_t stream) {
  (void)in_sizes; (void)n_in; (void)out_size; (void)ws_size;
  const float* query = (const float*)d_in[0];
  const float* key   = (const float*)d_in[1];
  const float* value = (const float*)d_in[2];
  const float* pos_k = (const float*)d_in[3];
  const float* pos_v = (const float*)d_in[4];
  const int*   mask  = (const int*)d_in[5];
  const float* rab   = (const float*)d_in[6];
  const float* Wq = (const float*)d_in[7];
  const float* bq = (const float*)d_in[8];
  const float* Wk = (const float*)d_in[9];
  const float* bk = (const float*)d_in[10];
  const float* Wv = (const float*)d_in[11];
  const float* bv = (const float*)d_in[12];
  const float* Wo = (const float*)d_in[13];
  const float* bo = (const float*)d_in[14];
  float* out = (float*)d_out;

  const size_t M2 = 2ull * 1024 * 1024;  // B*H*T*DK elements
  short* q = (short*)d_ws;
  short* k = q + M2;
  short* v = k + M2;
  short* S = v + M2;                       // 32M bf16 (B,H,T,T)
  float* X0 = (float*)(S + 32ull * 1024 * 1024);
  short* X = (short*)(X0 + M2);

  k_proj<<<dim3(16, 32), dim3(256), 0, stream>>>(query, Wq, bq, q, 0.125f);
  k_proj<<<dim3(16, 32), dim3(256), 0, stream>>>(key, Wk, bk, k, 1.0f);
  k_proj<<<dim3(16, 32), dim3(256), 0, stream>>>(value, Wv, bv, v, 1.0f);
  k_posk_bias<<<dim3(4, 1024), dim3(256), 0, stream>>>(q, pos_k, rab, mask, S);
  k_attn_softmax<<<dim3(32, 32), dim3(512), 0, stream>>>(q, k, S);
  k_posv<<<dim3(1024), dim3(256), 0, stream>>>(S, pos_v, X0);
  k_av<<<dim3(8, 32), dim3(256), 0, stream>>>(S, v, X0, X);
  k_oproj<<<dim3(16, 32), dim3(256), 0, stream>>>(X, Wo, bo, out);
}